// Round 6
// baseline (108.162 us; speedup 1.0000x reference)
//
#include <hip/hip_runtime.h>
#include <cstddef>

#define CCH 256
#define NPIX 4096
#define NB 8
#define INVCNT (1.0f/32768.0f)
#define INVN (1.0f/4096.0f)

typedef __bf16 bf16_t;
typedef __attribute__((ext_vector_type(8))) __bf16 bf16x8;
typedef __attribute__((ext_vector_type(4))) __bf16 bf16x4;
typedef __attribute__((ext_vector_type(4))) float f32x4;

// ---- workspace layout (float offsets) ----
#define OFF_S      0u          // 8*256 rowsums of Xj
#define OFF_AB     2048u       // A = Ww@gw  bf16 [256][256]
#define OFF_BMT    34816u      // BmT = thw^T@phw bf16 [256][256]
#define OFF_T1     67584u
#define OFF_R      67840u
#define OFF_W1     68096u
#define OFF_C1     68352u
#define OFF_G      68608u      // G bf16 8 x 256x256 (262144 floats)
#define OFF_MP     330752u     // M' bf16 8x65536 (262144 floats)
#define OFF_E      592896u     // e 8x256
#define OFF_RSP    594944u     // rowsum partials 8x4x256 (8192)
#define OFF_ZPS    603136u     // bn partial sums  [c 256][entry 512]
#define OFF_ZPQ    734208u     // bn partial sumsq [c 256][entry 512]
#define OFF_SCALE  865280u
#define OFF_SHIFT  865536u
#define OFF_GP     865792u     // Gram partials fp32 8*4*3*16384 (1572864)
#define OFF_XIT    2438656u    // Xi_t bf16 8*4096*256 (4194304 floats)

__device__ __forceinline__ void pack8(const float4& x, const float4& y, bf16x8& o) {
  o[0]=(bf16_t)x.x; o[1]=(bf16_t)x.y; o[2]=(bf16_t)x.z; o[3]=(bf16_t)x.w;
  o[4]=(bf16_t)y.x; o[5]=(bf16_t)y.y; o[6]=(bf16_t)y.z; o[7]=(bf16_t)y.w;
}

__device__ __forceinline__ void ld4(const float* p, float4& a0, float4& a1, float4& a2, float4& a3) {
  a0 = *(const float4*)p;       a1 = *(const float4*)(p + 4);
  a2 = *(const float4*)(p + 8); a3 = *(const float4*)(p + 12);
}

// ---------- generic 64x64-tile NN/TN fp32 matmul over K=256 ----------
template <bool ATRANS>
__device__ __forceinline__ void mm64_compute(const float* __restrict__ A,
                                             const float* __restrict__ B,
                                             int i0, int j0,
                                             float (&acc)[4][4],
                                             float (*s1)[65], float (*s2)[65]) {
  const int t = threadIdx.x, tx = t & 15, ty = t >> 4;
  for (int k0 = 0; k0 < 256; k0 += 64) {
#pragma unroll
    for (int it = 0; it < 4; ++it) {
      const int f = t + 256 * it;
      const int row = f >> 4, cc = (f & 15) * 4;
      float4 va;
      if (ATRANS)
        va = *(const float4*)(A + (size_t)(k0 + row) * CCH + i0 + cc);
      else
        va = *(const float4*)(A + (size_t)(i0 + row) * CCH + k0 + cc);
      const float4 vb = *(const float4*)(B + (size_t)(k0 + row) * CCH + j0 + cc);
      s1[row][cc + 0] = va.x; s1[row][cc + 1] = va.y; s1[row][cc + 2] = va.z; s1[row][cc + 3] = va.w;
      s2[row][cc + 0] = vb.x; s2[row][cc + 1] = vb.y; s2[row][cc + 2] = vb.z; s2[row][cc + 3] = vb.w;
    }
    __syncthreads();
#pragma unroll 4
    for (int kk = 0; kk < 64; ++kk) {
      float ar[4], br[4];
#pragma unroll
      for (int i = 0; i < 4; ++i) ar[i] = ATRANS ? s1[kk][4 * ty + i] : s1[4 * ty + i][kk];
#pragma unroll
      for (int j = 0; j < 4; ++j) br[j] = s2[kk][4 * tx + j];
#pragma unroll
      for (int i = 0; i < 4; ++i)
#pragma unroll
        for (int j = 0; j < 4; ++j) acc[i][j] += ar[i] * br[j];
    }
    __syncthreads();
  }
}

// ---------- mega-kernel bodies ----------
__device__ void pre_body(int blk, const float* Ww, const float* gw, const float* phw,
                         const float* thw, const float* gb, const float* phb,
                         const float* thb, float* ws, unsigned char* SMEM) {
  const int t = threadIdx.x;
  if (blk < 32) {
    float (*s1)[65] = (float(*)[65])SMEM;
    float (*s2)[65] = (float(*)[65])(SMEM + 16640);
    const int tb = blk & 15;
    const int i0 = (tb >> 2) * 64, j0 = (tb & 3) * 64;
    float acc[4][4] = {};
    if (blk < 16) mm64_compute<false>(Ww, gw, i0, j0, acc, s1, s2);   // A = Ww@gw
    else          mm64_compute<true >(thw, phw, i0, j0, acc, s1, s2); // BmT = thw^T@phw
    bf16_t* outp = (bf16_t*)(ws + (blk < 16 ? OFF_AB : OFF_BMT));
    const int tx = t & 15, ty = t >> 4;
#pragma unroll
    for (int i = 0; i < 4; ++i) {
      bf16x4 mv;
#pragma unroll
      for (int q = 0; q < 4; ++q) mv[q] = (bf16_t)acc[i][q];
      *(bf16x4*)&outp[(size_t)(i0 + 4 * ty + i) * CCH + j0 + 4 * tx] = mv;
    }
  } else {
    float t1v = 0.f, rv = 0.f, w1v = 0.f;
    for (int k = 0; k < 256; ++k) {
      t1v += phw[k * CCH + t] * thb[k];
      rv  += thw[k * CCH + t] * phb[k];
      w1v += Ww[t * CCH + k] * gb[k];
    }
    ws[OFF_T1 + t] = t1v; ws[OFF_R + t] = rv; ws[OFF_W1 + t] = w1v;
    float* red = (float*)SMEM;
    red[t] = phb[t] * thb[t];
    __syncthreads();
    for (int off = 128; off; off >>= 1) { if (t < off) red[t] += red[t + off]; __syncthreads(); }
    if (t == 0) ws[OFF_C1] = red[0];
  }
}

__device__ void cvtT_body(int bx, int b, const float* __restrict__ xi,
                          float* __restrict__ ws, unsigned char* SMEM) {
  bf16_t (*st)[72] = (bf16_t(*)[72])SMEM;
  const int c0 = (bx & 3) * 64;
  const int n0 = (bx >> 2) * 64;
  const float* X = xi + (size_t)b * CCH * NPIX;
  const int t = threadIdx.x;
  const int r = t >> 4, c4 = (t & 15) * 4;
#pragma unroll
  for (int it = 0; it < 4; ++it) {
    const int row = r + 16 * it;
    const float4 v = *(const float4*)(X + (size_t)(c0 + row) * NPIX + n0 + c4);
    st[row][c4 + 0] = (bf16_t)v.x; st[row][c4 + 1] = (bf16_t)v.y;
    st[row][c4 + 2] = (bf16_t)v.z; st[row][c4 + 3] = (bf16_t)v.w;
  }
  __syncthreads();
  bf16_t* Xit = (bf16_t*)(ws + OFF_XIT) + (size_t)b * NPIX * CCH;
  const int nr = t >> 2, cc = (t & 3) * 16;
  bf16x8 o0, o1;
#pragma unroll
  for (int j = 0; j < 8; ++j) o0[j] = st[cc + j][nr];
#pragma unroll
  for (int j = 0; j < 8; ++j) o1[j] = st[cc + 8 + j][nr];
  *(bf16x8*)(Xit + (size_t)(n0 + nr) * CCH + c0 + cc) = o0;
  *(bf16x8*)(Xit + (size_t)(n0 + nr) * CCH + c0 + cc + 8) = o1;
}

// split-K = 4: each gram block does K=1024
__device__ void gram_body(int bx, int b, const float* __restrict__ xj,
                          float* __restrict__ ws, unsigned char* SMEM) {
  const int ks = bx & 3;
  const int tl = bx >> 2;                 // 0:(0,0) 1:(0,1) 2:(1,1)
  const int i0 = (tl == 2) ? 128 : 0;
  const int j0 = (tl == 0) ? 0 : 128;
  const float* __restrict__ X = xj + (size_t)b * CCH * NPIX;
  bf16_t (*sA)[128][40] = (bf16_t(*)[128][40])SMEM;            // [2][128][40]
  bf16_t (*sB)[128][40] = (bf16_t(*)[128][40])(SMEM + 20480);  // [2][128][40]
  const int t = threadIdx.x;
  const int w = t >> 6, lane = t & 63;
  const f32x4 z4 = {0.f, 0.f, 0.f, 0.f};
  f32x4 acc[2][8];
#pragma unroll
  for (int fr = 0; fr < 2; ++fr)
#pragma unroll
    for (int fc = 0; fc < 8; ++fc) acc[fr][fc] = z4;
  float rsum = 0.f;
  const int k0 = ks * 1024;
  const int srow = t >> 1, sh16 = (t & 1) * 16;
  const bool haveB = (tl == 1);

  float4 a0, a1, a2, a3, b0, b1, b2, b3;
  auto LOAD = [&](int kc) {
    const float* pa = X + (size_t)(i0 + srow) * NPIX + k0 + kc + sh16;
    ld4(pa, a0, a1, a2, a3);
    rsum += a0.x + a0.y + a0.z + a0.w + a1.x + a1.y + a1.z + a1.w
          + a2.x + a2.y + a2.z + a2.w + a3.x + a3.y + a3.z + a3.w;
    if (haveB) {
      const float* pb = X + (size_t)(j0 + srow) * NPIX + k0 + kc + sh16;
      ld4(pb, b0, b1, b2, b3);
    }
  };
  auto WRITE = [&](int q) {
    bf16x8 u0, u1;
    pack8(a0, a1, u0); pack8(a2, a3, u1);
    *(bf16x8*)&sA[q][srow][sh16] = u0;
    *(bf16x8*)&sA[q][srow][sh16 + 8] = u1;
    if (haveB) {
      bf16x8 w0, w1;
      pack8(b0, b1, w0); pack8(b2, b3, w1);
      *(bf16x8*)&sB[q][srow][sh16] = w0;
      *(bf16x8*)&sB[q][srow][sh16 + 8] = w1;
    }
  };

  LOAD(0);
  WRITE(0);
  __syncthreads();
  int cur = 0;
  for (int kc8 = 0; kc8 < 32; ++kc8) {
    if (kc8 < 31) LOAD(32 * (kc8 + 1));
    const int fcol = 8 * (lane >> 4);
    const int lr = lane & 15;
    bf16_t (*SBc)[40] = haveB ? sB[cur] : sA[cur];
    const bf16x8 af0 = *(const bf16x8*)&sA[cur][32 * w + lr][fcol];
    const bf16x8 af1 = *(const bf16x8*)&sA[cur][32 * w + 16 + lr][fcol];
#pragma unroll
    for (int fc = 0; fc < 8; ++fc) {
      const bf16x8 bv = *(const bf16x8*)&SBc[16 * fc + lr][fcol];
      acc[0][fc] = __builtin_amdgcn_mfma_f32_16x16x32_bf16(af0, bv, acc[0][fc], 0, 0, 0);
      acc[1][fc] = __builtin_amdgcn_mfma_f32_16x16x32_bf16(af1, bv, acc[1][fc], 0, 0, 0);
    }
    if (kc8 < 31) WRITE(cur ^ 1);
    __syncthreads();
    cur ^= 1;
  }

  if (tl != 1) {
    const float o = __shfl_down(rsum, 1);
    if (!(t & 1)) ws[OFF_RSP + ((size_t)(b * 4 + ks)) * CCH + i0 + srow] = rsum + o;
  }
  float* GP = ws + OFF_GP + ((size_t)((b * 4 + ks) * 3 + tl)) * 16384;
  const int rbase = 32 * w + ((lane >> 4) << 2);
  const int col = lane & 15;
#pragma unroll
  for (int fr = 0; fr < 2; ++fr)
#pragma unroll
    for (int fc = 0; fc < 8; ++fc)
#pragma unroll
      for (int reg = 0; reg < 4; ++reg)
        GP[(size_t)(rbase + 16 * fr + reg) * 128 + 16 * fc + col] = acc[fr][fc][reg];
}

// ---------- mega: gram (x<12) | cvtT (12<=x<268) | pre (x>=268, y==0) ----------
__global__ __launch_bounds__(256) void k_mega(const float* __restrict__ xi,
                                              const float* __restrict__ xj,
                                              const float* __restrict__ Ww,
                                              const float* __restrict__ gw,
                                              const float* __restrict__ phw,
                                              const float* __restrict__ thw,
                                              const float* __restrict__ gb,
                                              const float* __restrict__ phb,
                                              const float* __restrict__ thb,
                                              float* __restrict__ ws) {
  __shared__ __align__(16) unsigned char SMEM[40960];
  const int bx = blockIdx.x, by = blockIdx.y;
  if (bx >= 268) {
    if (by == 0) pre_body(bx - 268, Ww, gw, phw, thw, gb, phb, thb, ws, SMEM);
    return;
  }
  if (bx >= 12) { cvtT_body(bx - 12, by, xi, ws, SMEM); return; }
  gram_body(bx, by, xj, ws, SMEM);
}

// ---------- reduce Gram partials -> G bf16 (+ mirror + finalize rowsums) ----------
__global__ __launch_bounds__(256) void k_greduce(float* __restrict__ ws) {
  const int b = blockIdx.y, bx = blockIdx.x, t = threadIdx.x;
  const float* BP = ws + OFF_GP + (size_t)b * 12 * 16384;
  bf16_t* Gb = (bf16_t*)(ws + OFF_G) + (size_t)b * 65536;
  if (bx < 128) {
    const int i = bx;
    const int j = t;
    const int tl = (j < 128) ? 0 : 1;
    const size_t idx = (size_t)i * 128 + (j & 127);
    float s = 0.f;
#pragma unroll
    for (int ks = 0; ks < 4; ++ks) s += BP[((size_t)ks * 3 + tl) * 16384 + idx];
    Gb[(size_t)i * CCH + j] = (bf16_t)s;
    if (j >= 128) Gb[(size_t)j * CCH + i] = (bf16_t)s;   // symmetric mirror
    if (t < 32) {
      const int row = (t < 16) ? i : (i + 128);
      const int l = t & 15;
      float v = (l < 4) ? ws[OFF_RSP + ((size_t)(b * 4 + l)) * CCH + row] : 0.f;
#pragma unroll
      for (int off = 8; off; off >>= 1) v += __shfl_down(v, off, 16);
      if (l == 0) ws[OFF_S + b * CCH + row] = v;
    }
  } else {
    const int r = 128 + ((bx - 128) << 1) + (t >> 7);
    const int j = 128 + (t & 127);
    const size_t idx = (size_t)(r - 128) * 128 + (j - 128);
    float s = 0.f;
#pragma unroll
    for (int ks = 0; ks < 4; ++ks) s += BP[((size_t)ks * 3 + 2) * 16384 + idx];
    Gb[(size_t)r * CCH + j] = (bf16_t)s;
  }
}

// ---------- fused K = A@G (MFMA), e, M' = f(K@BmT^T) (MFMA) ----------
__global__ __launch_bounds__(256) void k_kmmat(const float* __restrict__ Wb, float* __restrict__ ws) {
  const int b = blockIdx.y;
  const int i0 = blockIdx.x * 64;
  const int t = threadIdx.x;
  const int w = t >> 6, lane = t & 63;
  const int rg = w >> 1, cg = w & 1;
  const int lr = lane & 15, hi = lane >> 4;
  const int fcol = 8 * hi;

  __shared__ __align__(16) bf16_t sA[2][64][40];
  __shared__ __align__(16) bf16_t sB[2][256][40];
  __shared__ __align__(16) bf16_t sK[64][264];
  __shared__ float sS[256], sT1[256], sR[256], sW1[256], sVS[256];
  __shared__ float sU[64];
  __shared__ float red[256];
  __shared__ float sdt_sh;

  const bf16_t* Ab  = (const bf16_t*)(ws + OFF_AB);
  const bf16_t* BmT = (const bf16_t*)(ws + OFF_BMT);
  const bf16_t* Gb  = (const bf16_t*)(ws + OFF_G) + (size_t)b * 65536;

  sS[t]  = ws[OFF_S + b * CCH + t];
  sT1[t] = ws[OFF_T1 + t];
  sR[t]  = ws[OFF_R + t];
  sW1[t] = ws[OFF_W1 + t];
  __syncthreads();
  red[t] = sS[t] * sT1[t];
  __syncthreads();
  for (int off = 128; off; off >>= 1) { if (t < off) red[t] += red[t + off]; __syncthreads(); }
  if (t == 0) sdt_sh = red[0];
  {
    float a = 0.f;
    for (int k8 = 0; k8 < 256; k8 += 8) {
      const bf16x8 v = *(const bf16x8*)&BmT[(size_t)t * CCH + k8];
#pragma unroll
      for (int q = 0; q < 8; ++q) a += (float)v[q] * sS[k8 + q];
    }
    sVS[t] = a;
  }
  if (t < 64) {
    float a = 0.f;
    for (int k8 = 0; k8 < 256; k8 += 8) {
      const bf16x8 v = *(const bf16x8*)&Ab[(size_t)(i0 + t) * CCH + k8];
#pragma unroll
      for (int q = 0; q < 8; ++q) a += (float)v[q] * sS[k8 + q];
    }
    sU[t] = a;
  }

  const f32x4 z4 = {0.f, 0.f, 0.f, 0.f};
  const int arow = t >> 2, achk = (t & 3) * 8;

  // ---- phase B: K = A @ G (G symmetric -> B-op = G rows) ----
  f32x4 acc[2][8];
#pragma unroll
  for (int fr = 0; fr < 2; ++fr)
#pragma unroll
    for (int fc = 0; fc < 8; ++fc) acc[fr][fc] = z4;
  bf16x8 ra;
  bf16x8 gb8[4];
  auto LOADB = [&](int k) {
    ra = *(const bf16x8*)&Ab[(size_t)(i0 + arow) * CCH + k + achk];
#pragma unroll
    for (int h = 0; h < 4; ++h)
      gb8[h] = *(const bf16x8*)&Gb[(size_t)(64 * h + arow) * CCH + k + achk];
  };
  auto WRITEB = [&](int q) {
    *(bf16x8*)&sA[q][arow][achk] = ra;
#pragma unroll
    for (int h = 0; h < 4; ++h)
      *(bf16x8*)&sB[q][64 * h + arow][achk] = gb8[h];
  };
  LOADB(0);
  WRITEB(0);
  __syncthreads();
  int cur = 0;
  for (int ks = 0; ks < 8; ++ks) {
    if (ks < 7) LOADB(32 * (ks + 1));
    const bf16x8 af0 = *(const bf16x8*)&sA[cur][32 * rg + lr][fcol];
    const bf16x8 af1 = *(const bf16x8*)&sA[cur][32 * rg + 16 + lr][fcol];
#pragma unroll
    for (int fc = 0; fc < 8; ++fc) {
      const bf16x8 bv = *(const bf16x8*)&sB[cur][128 * cg + 16 * fc + lr][fcol];
      acc[0][fc] = __builtin_amdgcn_mfma_f32_16x16x32_bf16(af0, bv, acc[0][fc], 0, 0, 0);
      acc[1][fc] = __builtin_amdgcn_mfma_f32_16x16x32_bf16(af1, bv, acc[1][fc], 0, 0, 0);
    }
    if (ks < 7) WRITEB(cur ^ 1);
    __syncthreads();
    cur ^= 1;
  }
  // K -> LDS bf16
#pragma unroll
  for (int fr = 0; fr < 2; ++fr)
#pragma unroll
    for (int fc = 0; fc < 8; ++fc)
#pragma unroll
      for (int reg = 0; reg < 4; ++reg)
        sK[32 * rg + 16 * fr + 4 * hi + reg][128 * cg + 16 * fc + lr] = (bf16_t)acc[fr][fc][reg];
  __syncthreads();

  // e (t<64): needs K row dot t1
  if (t < 64) {
    float dot = 0.f;
    for (int k8 = 0; k8 < 256; k8 += 8) {
      const bf16x8 v = *(const bf16x8*)&sK[t][k8];
#pragma unroll
      for (int q = 0; q < 8; ++q) dot += (float)v[q] * sT1[k8 + q];
    }
    const float c1 = ws[OFF_C1];
    const float ui = sU[t], w1i = sW1[i0 + t];
    ws[OFF_E + b * CCH + i0 + t] = INVN * (dot + c1 * ui + sdt_sh * w1i) + c1 * w1i + Wb[i0 + t];
  }

  // ---- phase C: Mcore = K @ Bm ----
  f32x4 acc2[2][8];
#pragma unroll
  for (int fr = 0; fr < 2; ++fr)
#pragma unroll
    for (int fc = 0; fc < 8; ++fc) acc2[fr][fc] = z4;
  bf16x8 rb[4];
  auto LOADC = [&](int k) {
#pragma unroll
    for (int h = 0; h < 4; ++h)
      rb[h] = *(const bf16x8*)&BmT[(size_t)(64 * h + arow) * CCH + k + achk];
  };
  auto WRITEC = [&](int q) {
#pragma unroll
    for (int h = 0; h < 4; ++h)
      *(bf16x8*)&sB[q][64 * h + arow][achk] = rb[h];
  };
  LOADC(0);
  WRITEC(0);
  __syncthreads();
  cur = 0;
  for (int ks = 0; ks < 8; ++ks) {
    if (ks < 7) LOADC(32 * (ks + 1));
    const bf16x8 af0 = *(const bf16x8*)&sK[32 * rg + lr][32 * ks + fcol];
    const bf16x8 af1 = *(const bf16x8*)&sK[32 * rg + 16 + lr][32 * ks + fcol];
#pragma unroll
    for (int fc = 0; fc < 8; ++fc) {
      const bf16x8 bv = *(const bf16x8*)&sB[cur][128 * cg + 16 * fc + lr][fcol];
      acc2[0][fc] = __builtin_amdgcn_mfma_f32_16x16x32_bf16(af0, bv, acc2[0][fc], 0, 0, 0);
      acc2[1][fc] = __builtin_amdgcn_mfma_f32_16x16x32_bf16(af1, bv, acc2[1][fc], 0, 0, 0);
    }
    if (ks < 7) WRITEC(cur ^ 1);
    __syncthreads();
    cur ^= 1;
  }

  // epilogue: M' = (acc2 + u r^T + w1 vs^T)/N + w1 r^T + I  (bf16)
  bf16_t* Mp = (bf16_t*)(ws + OFF_MP) + (size_t)b * 65536;
#pragma unroll
  for (int fr = 0; fr < 2; ++fr)
#pragma unroll
    for (int fc = 0; fc < 8; ++fc) {
      const int j = 128 * cg + 16 * fc + lr;
      const float rj = sR[j], vsj = sVS[j];
#pragma unroll
      for (int reg = 0; reg < 4; ++reg) {
        const int il = 32 * rg + 16 * fr + 4 * hi + reg;
        const float ui = sU[il], w1i = sW1[i0 + il];
        float m = (acc2[fr][fc][reg] + ui * rj + w1i * vsj) * INVN + w1i * rj;
        if (i0 + il == j) m += 1.0f;
        Mp[(size_t)(i0 + il) * CCH + j] = (bf16_t)m;
      }
    }
}

// ---------- Z^T 64-n tiles via MFMA, dbuf. APPLY=0: BN partials; 1: coalesced out ----------
template <int APPLY>
__global__ __launch_bounds__(256) void k_zmm(float* __restrict__ ws, float* __restrict__ out) {
  const int b = blockIdx.y, nblk = blockIdx.x;      // 64 nblks of 64
  const int n0 = nblk * 64;
  const int t = threadIdx.x;
  const int w = t >> 6, lane = t & 63;
  const int rg = w >> 1, cg = w & 1;
  __shared__ __align__(16) unsigned char SMEMu[51200];   // sA(10240)+sB(40960); sZ unions it
  bf16_t (*sA)[64][40]  = (bf16_t(*)[64][40])SMEMu;
  bf16_t (*sB)[256][40] = (bf16_t(*)[256][40])(SMEMu + 10240);
  float (*sZ)[68]       = (float(*)[68])SMEMu;           // [128 c-half][68 n] fp32
  __shared__ float sC1[256], sC2[256];
  __shared__ float redS[4][128], redQ[4][128];
  {
    const float e = ws[OFF_E + b * CCH + t];
    if (APPLY) {
      const float sc = ws[OFF_SCALE + t];
      sC1[t] = sc;
      sC2[t] = e * sc + ws[OFF_SHIFT + t];
    } else {
      sC1[t] = e;
    }
  }
  const bf16_t* Xit = (const bf16_t*)(ws + OFF_XIT) + (size_t)b * NPIX * CCH;
  const bf16_t* Mp = (const bf16_t*)(ws + OFF_MP) + (size_t)b * 65536;
  const f32x4 z4 = {0.f, 0.f, 0.f, 0.f};
  f32x4 acc[2][8];
#pragma unroll
  for (int fr = 0; fr < 2; ++fr)
#pragma unroll
    for (int fc = 0; fc < 8; ++fc) acc[fr][fc] = z4;
  const int arow = t >> 2, achk = (t & 3) * 8;
  bf16x8 ra, rb0, rb1, rb2, rb3;
  ra  = *(const bf16x8*)(Xit + (size_t)(n0 + arow) * CCH + achk);
  rb0 = *(const bf16x8*)(Mp + (size_t)(arow)       * CCH + achk);
  rb1 = *(const bf16x8*)(Mp + (size_t)(64 + arow)  * CCH + achk);
  rb2 = *(const bf16x8*)(Mp + (size_t)(128 + arow) * CCH + achk);
  rb3 = *(const bf16x8*)(Mp + (size_t)(192 + arow) * CCH + achk);
  *(bf16x8*)&sA[0][arow][achk] = ra;
  *(bf16x8*)&sB[0][arow][achk] = rb0;
  *(bf16x8*)&sB[0][64 + arow][achk] = rb1;
  *(bf16x8*)&sB[0][128 + arow][achk] = rb2;
  *(bf16x8*)&sB[0][192 + arow][achk] = rb3;
  __syncthreads();
  int cur = 0;
  for (int ks = 0; ks < 8; ++ks) {
    const int nk = 32 * (ks + 1);
    if (ks < 7) {
      ra  = *(const bf16x8*)(Xit + (size_t)(n0 + arow) * CCH + nk + achk);
      rb0 = *(const bf16x8*)(Mp + (size_t)(arow)       * CCH + nk + achk);
      rb1 = *(const bf16x8*)(Mp + (size_t)(64 + arow)  * CCH + nk + achk);
      rb2 = *(const bf16x8*)(Mp + (size_t)(128 + arow) * CCH + nk + achk);
      rb3 = *(const bf16x8*)(Mp + (size_t)(192 + arow) * CCH + nk + achk);
    }
    const int fcol = 8 * (lane >> 4);
    const int lr = lane & 15;
    const bf16x8 af0 = *(const bf16x8*)&sA[cur][32 * rg + lr][fcol];
    const bf16x8 af1 = *(const bf16x8*)&sA[cur][32 * rg + 16 + lr][fcol];
#pragma unroll
    for (int fc = 0; fc < 8; ++fc) {
      const bf16x8 bv = *(const bf16x8*)&sB[cur][128 * cg + 16 * fc + lr][fcol];
      acc[0][fc] = __builtin_amdgcn_mfma_f32_16x16x32_bf16(af0, bv, acc[0][fc], 0, 0, 0);
      acc[1][fc] = __builtin_amdgcn_mfma_f32_16x16x32_bf16(af1, bv, acc[1][fc], 0, 0, 0);
    }
    if (ks < 7) {
      *(bf16x8*)&sA[cur ^ 1][arow][achk] = ra;
      *(bf16x8*)&sB[cur ^ 1][arow][achk] = rb0;
      *(bf16x8*)&sB[cur ^ 1][64 + arow][achk] = rb1;
      *(bf16x8*)&sB[cur ^ 1][128 + arow][achk] = rb2;
      *(bf16x8*)&sB[cur ^ 1][192 + arow][achk] = rb3;
    }
    __syncthreads();
    cur ^= 1;
  }
  if (APPLY) {
    const int lr = lane & 15, hi = lane >> 4;
    // two c-halves; bounce Z tile through LDS for coalesced out writes
    for (int h = 0; h < 2; ++h) {
      __syncthreads();
      if (cg == h) {
#pragma unroll
        for (int fr = 0; fr < 2; ++fr)
#pragma unroll
          for (int fc = 0; fc < 8; ++fc)
#pragma unroll
            for (int reg = 0; reg < 4; ++reg)
              sZ[16 * fc + lr][32 * rg + 16 * fr + 4 * hi + reg] = acc[fr][fc][reg];
      }
      __syncthreads();
      const int rr = t >> 1, nq = (t & 1) * 32;
      const int c = 128 * h + rr;
      const float sc = sC1[c], b2 = sC2[c];
      float* op = out + ((size_t)b * CCH + c) * NPIX + n0 + nq;
#pragma unroll
      for (int q = 0; q < 8; ++q) {
        float4 v;
        v.x = sZ[rr][nq + 4 * q + 0] * sc + b2;
        v.y = sZ[rr][nq + 4 * q + 1] * sc + b2;
        v.z = sZ[rr][nq + 4 * q + 2] * sc + b2;
        v.w = sZ[rr][nq + 4 * q + 3] * sc + b2;
        *(float4*)(op + 4 * q) = v;
      }
    }
  } else {
    float ps[8], pq[8];
#pragma unroll
    for (int fc = 0; fc < 8; ++fc) {
      const int c = 128 * cg + 16 * fc + (lane & 15);
      const float e = sC1[c];
      float s = 0.f, q = 0.f;
#pragma unroll
      for (int fr = 0; fr < 2; ++fr)
#pragma unroll
        for (int reg = 0; reg < 4; ++reg) {
          const float z = acc[fr][fc][reg] + e;
          s += z; q += z * z;
        }
      s += __shfl_xor(s, 16); s += __shfl_xor(s, 32);
      q += __shfl_xor(q, 16); q += __shfl_xor(q, 32);
      ps[fc] = s; pq[fc] = q;
    }
    if (lane < 16) {
#pragma unroll
      for (int fc = 0; fc < 8; ++fc) {
        redS[w][16 * fc + lane] = ps[fc];
        redQ[w][16 * fc + lane] = pq[fc];
      }
    }
    __syncthreads();
    if (t < 256) {
      const int cg2 = t >> 7, c = t & 127;
      float s = 0.f, q = 0.f;
#pragma unroll
      for (int rg2 = 0; rg2 < 2; ++rg2) {
        s += redS[rg2 * 2 + cg2][c];
        q += redQ[rg2 * 2 + cg2][c];
      }
      ws[OFF_ZPS + (size_t)t * 512 + b * 64 + nblk] = s;
      ws[OFF_ZPQ + (size_t)t * 512 + b * 64 + nblk] = q;
    }
  }
}

// ---------- BN stats -> scale/shift ----------
__global__ __launch_bounds__(64) void k_bnstats(const float* __restrict__ gamma,
                                                const float* __restrict__ beta,
                                                float* __restrict__ ws) {
  const int c = blockIdx.x, t = threadIdx.x;
  const float* PS = ws + OFF_ZPS + (size_t)c * 512;
  const float* PQ = ws + OFF_ZPQ + (size_t)c * 512;
  float s = 0.f, q = 0.f;
#pragma unroll
  for (int e = 0; e < 8; ++e) { s += PS[t + 64 * e]; q += PQ[t + 64 * e]; }
#pragma unroll
  for (int off = 32; off; off >>= 1) { s += __shfl_down(s, off); q += __shfl_down(q, off); }
  if (t == 0) {
    const float mean = s * INVCNT;
    const float var = q * INVCNT - mean * mean;
    const float sc = gamma[c] * rsqrtf(var + 1e-5f);
    ws[OFF_SCALE + c] = sc;
    ws[OFF_SHIFT + c] = beta[c] - mean * sc;
  }
}

extern "C" void kernel_launch(void* const* d_in, const int* in_sizes, int n_in,
                              void* d_out, int out_size, void* d_ws, size_t ws_size,
                              hipStream_t stream) {
  const float* xi  = (const float*)d_in[0];
  const float* xj  = (const float*)d_in[1];
  const float* gw  = (const float*)d_in[2];
  const float* gb  = (const float*)d_in[3];
  const float* thw = (const float*)d_in[4];
  const float* thb = (const float*)d_in[5];
  const float* phw = (const float*)d_in[6];
  const float* phb = (const float*)d_in[7];
  const float* Ww  = (const float*)d_in[8];
  const float* Wb  = (const float*)d_in[9];
  const float* gamma = (const float*)d_in[10];
  const float* beta  = (const float*)d_in[11];
  float* ws = (float*)d_ws;
  float* out = (float*)d_out;

  k_mega<<<dim3(301, 8), 256, 0, stream>>>(xi, xj, Ww, gw, phw, thw, gb, phb, thb, ws);
  k_greduce<<<dim3(192, 8), 256, 0, stream>>>(ws);
  k_kmmat<<<dim3(4, 8), 256, 0, stream>>>(Wb, ws);
  k_zmm<0><<<dim3(64, 8), 256, 0, stream>>>(ws, out);
  k_bnstats<<<256, 64, 0, stream>>>(gamma, beta, ws);
  k_zmm<1><<<dim3(64, 8), 256, 0, stream>>>(ws, out);
}

// Round 7
// 87.460 us; speedup vs baseline: 1.2367x; 1.2367x over previous
//
#include <hip/hip_runtime.h>
#include <cstddef>

#define CCH 256
#define NPIX 4096
#define NB 8
#define INVCNT (1.0f/32768.0f)
#define INVN (1.0f/4096.0f)

typedef __bf16 bf16_t;
typedef __attribute__((ext_vector_type(8))) __bf16 bf16x8;
typedef __attribute__((ext_vector_type(4))) __bf16 bf16x4;
typedef __attribute__((ext_vector_type(4))) float f32x4;

// ---- workspace layout (float offsets) ----
#define OFF_S      0u          // 8*256 rowsums of Xj
#define OFF_AB     2048u       // A = Ww@gw  bf16 [256][256]
#define OFF_BMT    34816u      // BmT = thw^T@phw bf16 [256][256]
#define OFF_T1     67584u
#define OFF_R      67840u
#define OFF_W1     68096u
#define OFF_C1     68352u
#define OFF_G      68608u      // G bf16 8 x 256x256 (262144 floats)
#define OFF_MP     330752u     // M' bf16 8x65536 (262144 floats)
#define OFF_E      592896u     // e 8x256
#define OFF_RSP    594944u     // rowsum partials 8x16x256 (32768)
#define OFF_ZPS    627712u     // bn partial sums  [c 256][entry 512]
#define OFF_ZPQ    758784u     // bn partial sumsq [c 256][entry 512]
#define OFF_SCALE  889856u
#define OFF_SHIFT  890112u
#define OFF_GP     890368u     // Gram partials bf16 8*16*65536 el (4194304 floats)
#define OFF_XIT    5084672u    // Xi_t bf16 8*4096*256 (4194304 floats)

__device__ __forceinline__ void pack8(const float4& x, const float4& y, bf16x8& o) {
  o[0]=(bf16_t)x.x; o[1]=(bf16_t)x.y; o[2]=(bf16_t)x.z; o[3]=(bf16_t)x.w;
  o[4]=(bf16_t)y.x; o[5]=(bf16_t)y.y; o[6]=(bf16_t)y.z; o[7]=(bf16_t)y.w;
}

__device__ __forceinline__ void ld4(const float* p, float4& a0, float4& a1, float4& a2, float4& a3) {
  a0 = *(const float4*)p;       a1 = *(const float4*)(p + 4);
  a2 = *(const float4*)(p + 8); a3 = *(const float4*)(p + 12);
}

// ---------- 64x64-tile NN/TN fp32 matmul over K=256, 512 threads ----------
template <bool ATRANS>
__device__ __forceinline__ void mm64v(const float* __restrict__ A,
                                      const float* __restrict__ B,
                                      int i0, int j0,
                                      float (&acc)[2][4],
                                      float (*s1)[65], float (*s2)[65]) {
  const int t = threadIdx.x, tx = t & 15, ty = t >> 4;   // ty 0..31 -> rows 2ty,2ty+1
  for (int k0 = 0; k0 < 256; k0 += 64) {
#pragma unroll
    for (int it = 0; it < 2; ++it) {
      const int f = t + 512 * it;
      const int row = f >> 4, cc = (f & 15) * 4;
      float4 va;
      if (ATRANS)
        va = *(const float4*)(A + (size_t)(k0 + row) * CCH + i0 + cc);
      else
        va = *(const float4*)(A + (size_t)(i0 + row) * CCH + k0 + cc);
      const float4 vb = *(const float4*)(B + (size_t)(k0 + row) * CCH + j0 + cc);
      s1[row][cc + 0] = va.x; s1[row][cc + 1] = va.y; s1[row][cc + 2] = va.z; s1[row][cc + 3] = va.w;
      s2[row][cc + 0] = vb.x; s2[row][cc + 1] = vb.y; s2[row][cc + 2] = vb.z; s2[row][cc + 3] = vb.w;
    }
    __syncthreads();
#pragma unroll 4
    for (int kk = 0; kk < 64; ++kk) {
      float ar[2], br[4];
#pragma unroll
      for (int i = 0; i < 2; ++i) ar[i] = ATRANS ? s1[kk][2 * ty + i] : s1[2 * ty + i][kk];
#pragma unroll
      for (int j = 0; j < 4; ++j) br[j] = s2[kk][4 * tx + j];
#pragma unroll
      for (int i = 0; i < 2; ++i)
#pragma unroll
        for (int j = 0; j < 4; ++j) acc[i][j] += ar[i] * br[j];
    }
    __syncthreads();
  }
}

// ---------- mega bodies (512 threads each) ----------
__device__ void pre_body(int blk, const float* Ww, const float* gw, const float* phw,
                         const float* thw, const float* gb, const float* phb,
                         const float* thb, float* ws, unsigned char* SMEM) {
  const int t = threadIdx.x;
  if (blk < 32) {
    float (*s1)[65] = (float(*)[65])SMEM;
    float (*s2)[65] = (float(*)[65])(SMEM + 16640);
    const int tb = blk & 15;
    const int i0 = (tb >> 2) * 64, j0 = (tb & 3) * 64;
    float acc[2][4] = {};
    if (blk < 16) mm64v<false>(Ww, gw, i0, j0, acc, s1, s2);   // A = Ww@gw
    else          mm64v<true >(thw, phw, i0, j0, acc, s1, s2); // BmT = thw^T@phw
    bf16_t* outp = (bf16_t*)(ws + (blk < 16 ? OFF_AB : OFF_BMT));
    const int tx = t & 15, ty = t >> 4;
#pragma unroll
    for (int i = 0; i < 2; ++i) {
      bf16x4 mv;
#pragma unroll
      for (int q = 0; q < 4; ++q) mv[q] = (bf16_t)acc[i][q];
      *(bf16x4*)&outp[(size_t)(i0 + 2 * ty + i) * CCH + j0 + 4 * tx] = mv;
    }
  } else {
    if (t < 256) {
      float t1v = 0.f, rv = 0.f, w1v = 0.f;
      for (int k = 0; k < 256; ++k) {
        t1v += phw[k * CCH + t] * thb[k];
        rv  += thw[k * CCH + t] * phb[k];
        w1v += Ww[t * CCH + k] * gb[k];
      }
      ws[OFF_T1 + t] = t1v; ws[OFF_R + t] = rv; ws[OFF_W1 + t] = w1v;
    }
    float* red = (float*)SMEM;
    red[t] = (t < 256) ? phb[t] * thb[t] : 0.f;
    __syncthreads();
    for (int off = 256; off; off >>= 1) { if (t < off) red[t] += red[t + off]; __syncthreads(); }
    if (t == 0) ws[OFF_C1] = red[0];
  }
}

__device__ void cvtT_body(int bx, int b, const float* __restrict__ xi,
                          float* __restrict__ ws, unsigned char* SMEM) {
  bf16_t (*st)[72] = (bf16_t(*)[72])SMEM;     // [128 c][72 n]
  const int c0 = (bx & 1) * 128;
  const int n0 = (bx >> 1) * 64;
  const float* X = xi + (size_t)b * CCH * NPIX;
  const int t = threadIdx.x;
  const int r = t >> 2, c4 = (t & 3) * 16;
  {
    float4 a0, a1, a2, a3;
    ld4(X + (size_t)(c0 + r) * NPIX + n0 + c4, a0, a1, a2, a3);
    bf16x8 u0, u1;
    pack8(a0, a1, u0); pack8(a2, a3, u1);
    *(bf16x8*)&st[r][c4] = u0;
    *(bf16x8*)&st[r][c4 + 8] = u1;
  }
  __syncthreads();
  bf16_t* Xit = (bf16_t*)(ws + OFF_XIT) + (size_t)b * NPIX * CCH;
  const int nr = t >> 3, cc = (t & 7) * 16;
  bf16x8 o0, o1;
#pragma unroll
  for (int j = 0; j < 8; ++j) o0[j] = st[cc + j][nr];
#pragma unroll
  for (int j = 0; j < 8; ++j) o1[j] = st[cc + 8 + j][nr];
  *(bf16x8*)(Xit + (size_t)(n0 + nr) * CCH + c0 + cc) = o0;
  *(bf16x8*)(Xit + (size_t)(n0 + nr) * CCH + c0 + cc + 8) = o1;
}

// fused full-matrix gram: one block per (b, ks): reads 256 rows x 256 k ONCE
__device__ void gram_body(int ks, int b, const float* __restrict__ xj,
                          float* __restrict__ ws, unsigned char* SMEM) {
  const float* __restrict__ X = xj + (size_t)b * CCH * NPIX;
  bf16_t (*sA)[256][40] = (bf16_t(*)[256][40])SMEM;    // [2][256][40] = 40960 B
  const int t = threadIdx.x;
  const int w = t >> 6, lane = t & 63;
  const int wr = w >> 1, wc = w & 1;
  const int lr = lane & 15, hi = lane >> 4;
  const int fcol = 8 * hi;
  const f32x4 z4 = {0.f, 0.f, 0.f, 0.f};
  f32x4 acc[4][8];
#pragma unroll
  for (int fr = 0; fr < 4; ++fr)
#pragma unroll
    for (int fc = 0; fc < 8; ++fc) acc[fr][fc] = z4;
  float rsum = 0.f;
  const int k0 = ks * 256;
  const int srow = t >> 1, sh16 = (t & 1) * 16;

  float4 a0, a1, a2, a3;
  auto LOAD = [&](int kc) {
    ld4(X + (size_t)srow * NPIX + k0 + kc + sh16, a0, a1, a2, a3);
    rsum += a0.x + a0.y + a0.z + a0.w + a1.x + a1.y + a1.z + a1.w
          + a2.x + a2.y + a2.z + a2.w + a3.x + a3.y + a3.z + a3.w;
  };
  auto WRITE = [&](int q) {
    bf16x8 u0, u1;
    pack8(a0, a1, u0); pack8(a2, a3, u1);
    *(bf16x8*)&sA[q][srow][sh16] = u0;
    *(bf16x8*)&sA[q][srow][sh16 + 8] = u1;
  };

  LOAD(0);
  WRITE(0);
  __syncthreads();
  int cur = 0;
  for (int kc8 = 0; kc8 < 8; ++kc8) {
    if (kc8 < 7) LOAD(32 * (kc8 + 1));
    bf16x8 af[4];
#pragma unroll
    for (int fr = 0; fr < 4; ++fr)
      af[fr] = *(const bf16x8*)&sA[cur][64 * wr + 16 * fr + lr][fcol];
#pragma unroll
    for (int fc = 0; fc < 8; ++fc) {
      const bf16x8 bv = *(const bf16x8*)&sA[cur][128 * wc + 16 * fc + lr][fcol];
#pragma unroll
      for (int fr = 0; fr < 4; ++fr)
        acc[fr][fc] = __builtin_amdgcn_mfma_f32_16x16x32_bf16(af[fr], bv, acc[fr][fc], 0, 0, 0);
    }
    if (kc8 < 7) WRITE(cur ^ 1);
    __syncthreads();
    cur ^= 1;
  }

  {
    const float o = __shfl_down(rsum, 1);
    if (!(t & 1)) ws[OFF_RSP + ((size_t)(b * 16 + ks)) * CCH + srow] = rsum + o;
  }
  bf16_t* GPp = (bf16_t*)(ws + OFF_GP) + (size_t)(b * 16 + ks) * 65536;
#pragma unroll
  for (int fr = 0; fr < 4; ++fr)
#pragma unroll
    for (int fc = 0; fc < 8; ++fc)
#pragma unroll
      for (int reg = 0; reg < 4; ++reg)
        GPp[(size_t)(64 * wr + 16 * fr + 4 * hi + reg) * CCH + 128 * wc + 16 * fc + lr] =
            (bf16_t)acc[fr][fc][reg];
}

// ---------- mega: gram (x<16) | cvtT (16<=x<144) | pre (x>=144, y==0) ----------
__global__ __launch_bounds__(512) void k_mega(const float* __restrict__ xi,
                                              const float* __restrict__ xj,
                                              const float* __restrict__ Ww,
                                              const float* __restrict__ gw,
                                              const float* __restrict__ phw,
                                              const float* __restrict__ thw,
                                              const float* __restrict__ gb,
                                              const float* __restrict__ phb,
                                              const float* __restrict__ thb,
                                              float* __restrict__ ws) {
  __shared__ __align__(16) unsigned char SMEM[40960];
  const int bx = blockIdx.x, by = blockIdx.y;
  if (bx >= 144) {
    if (by == 0) pre_body(bx - 144, Ww, gw, phw, thw, gb, phb, thb, ws, SMEM);
    return;
  }
  if (bx >= 16) { cvtT_body(bx - 16, by, xi, ws, SMEM); return; }
  gram_body(bx, by, xj, ws, SMEM);
}

// ---------- reduce 16 bf16 Gram partials -> G bf16; finalize rowsums ----------
__global__ __launch_bounds__(256) void k_greduce(float* __restrict__ ws) {
  const int b = blockIdx.y, bx = blockIdx.x, t = threadIdx.x;
  const bf16_t* GPp = (const bf16_t*)(ws + OFF_GP) + (size_t)b * 16 * 65536;
  bf16_t* Gb = (bf16_t*)(ws + OFF_G) + (size_t)b * 65536;
  // block handles 8 rows: row = bx*8 + (t>>5), 8 cols per thread
  const int row = bx * 8 + (t >> 5);
  const int j8 = (t & 31) * 8;
  float s[8] = {};
#pragma unroll
  for (int ks = 0; ks < 16; ++ks) {
    const bf16x8 v = *(const bf16x8*)&GPp[(size_t)ks * 65536 + row * CCH + j8];
#pragma unroll
    for (int q = 0; q < 8; ++q) s[q] += (float)v[q];
  }
  bf16x8 o;
#pragma unroll
  for (int q = 0; q < 8; ++q) o[q] = (bf16_t)s[q];
  *(bf16x8*)&Gb[(size_t)row * CCH + j8] = o;
  if (t < 128) {
    const int rr = bx * 8 + (t >> 4), l = t & 15;
    float v = ws[OFF_RSP + ((size_t)(b * 16 + l)) * CCH + rr];
#pragma unroll
    for (int off = 8; off; off >>= 1) v += __shfl_down(v, off, 16);
    if (l == 0) ws[OFF_S + b * CCH + rr] = v;
  }
}

// ---------- fused K = A@G (MFMA), e, M' = f(K@Bm) (MFMA); 32-row blocks ----------
__global__ __launch_bounds__(256) void k_kmmat(const float* __restrict__ Wb, float* __restrict__ ws) {
  const int b = blockIdx.y;
  const int i0 = blockIdx.x * 32;
  const int t = threadIdx.x;
  const int w = t >> 6, lane = t & 63;
  const int rg = w >> 1, cg = w & 1;
  const int lr = lane & 15, hi = lane >> 4;
  const int fcol = 8 * hi;

  __shared__ __align__(16) bf16_t sA[2][32][40];
  __shared__ __align__(16) bf16_t sB[2][256][40];
  __shared__ __align__(16) bf16_t sK[32][264];
  __shared__ float sS[256], sT1[256], sR[256], sW1[256], sVS[256];
  __shared__ float sU[32];
  __shared__ float red[256];
  __shared__ float sdt_sh;

  const bf16_t* Ab  = (const bf16_t*)(ws + OFF_AB);
  const bf16_t* BmT = (const bf16_t*)(ws + OFF_BMT);
  const bf16_t* Gb  = (const bf16_t*)(ws + OFF_G) + (size_t)b * 65536;

  sS[t]  = ws[OFF_S + b * CCH + t];
  sT1[t] = ws[OFF_T1 + t];
  sR[t]  = ws[OFF_R + t];
  sW1[t] = ws[OFF_W1 + t];
  __syncthreads();
  red[t] = sS[t] * sT1[t];
  __syncthreads();
  for (int off = 128; off; off >>= 1) { if (t < off) red[t] += red[t + off]; __syncthreads(); }
  if (t == 0) sdt_sh = red[0];
  {
    float a = 0.f;
    for (int k8 = 0; k8 < 256; k8 += 8) {
      const bf16x8 v = *(const bf16x8*)&BmT[(size_t)t * CCH + k8];
#pragma unroll
      for (int q = 0; q < 8; ++q) a += (float)v[q] * sS[k8 + q];
    }
    sVS[t] = a;
  }
  if (t < 32) {
    float a = 0.f;
    for (int k8 = 0; k8 < 256; k8 += 8) {
      const bf16x8 v = *(const bf16x8*)&Ab[(size_t)(i0 + t) * CCH + k8];
#pragma unroll
      for (int q = 0; q < 8; ++q) a += (float)v[q] * sS[k8 + q];
    }
    sU[t] = a;
  }

  const f32x4 z4 = {0.f, 0.f, 0.f, 0.f};
  const int arow = t >> 2, achk = (t & 3) * 8;     // B staging: 64-row groups x4
  const int arA = t >> 2, akA = (t & 3) * 8;       // A staging (t<128): 32 rows

  // ---- phase B: K = A @ G (G symmetric) ----
  f32x4 acc[8];
#pragma unroll
  for (int fc = 0; fc < 8; ++fc) acc[fc] = z4;
  bf16x8 ra;
  bf16x8 gb8[4];
  auto LOADB = [&](int k) {
    if (t < 128) ra = *(const bf16x8*)&Ab[(size_t)(i0 + arA) * CCH + k + akA];
#pragma unroll
    for (int h = 0; h < 4; ++h)
      gb8[h] = *(const bf16x8*)&Gb[(size_t)(64 * h + arow) * CCH + k + achk];
  };
  auto WRITEB = [&](int q) {
    if (t < 128) *(bf16x8*)&sA[q][arA][akA] = ra;
#pragma unroll
    for (int h = 0; h < 4; ++h)
      *(bf16x8*)&sB[q][64 * h + arow][achk] = gb8[h];
  };
  LOADB(0);
  WRITEB(0);
  __syncthreads();
  int cur = 0;
  for (int ks = 0; ks < 8; ++ks) {
    if (ks < 7) LOADB(32 * (ks + 1));
    const bf16x8 af = *(const bf16x8*)&sA[cur][16 * rg + lr][fcol];
#pragma unroll
    for (int fc = 0; fc < 8; ++fc) {
      const bf16x8 bv = *(const bf16x8*)&sB[cur][128 * cg + 16 * fc + lr][fcol];
      acc[fc] = __builtin_amdgcn_mfma_f32_16x16x32_bf16(af, bv, acc[fc], 0, 0, 0);
    }
    if (ks < 7) WRITEB(cur ^ 1);
    __syncthreads();
    cur ^= 1;
  }
  // K -> LDS bf16
#pragma unroll
  for (int fc = 0; fc < 8; ++fc)
#pragma unroll
    for (int reg = 0; reg < 4; ++reg)
      sK[16 * rg + 4 * hi + reg][128 * cg + 16 * fc + lr] = (bf16_t)acc[fc][reg];
  __syncthreads();

  // e (t<32)
  if (t < 32) {
    float dot = 0.f;
    for (int k8 = 0; k8 < 256; k8 += 8) {
      const bf16x8 v = *(const bf16x8*)&sK[t][k8];
#pragma unroll
      for (int q = 0; q < 8; ++q) dot += (float)v[q] * sT1[k8 + q];
    }
    const float c1 = ws[OFF_C1];
    const float ui = sU[t], w1i = sW1[i0 + t];
    ws[OFF_E + b * CCH + i0 + t] = INVN * (dot + c1 * ui + sdt_sh * w1i) + c1 * w1i + Wb[i0 + t];
  }

  // ---- phase C: Mcore = K @ Bm ----
  f32x4 acc2[8];
#pragma unroll
  for (int fc = 0; fc < 8; ++fc) acc2[fc] = z4;
  bf16x8 rb[4];
  auto LOADC = [&](int k) {
#pragma unroll
    for (int h = 0; h < 4; ++h)
      rb[h] = *(const bf16x8*)&BmT[(size_t)(64 * h + arow) * CCH + k + achk];
  };
  auto WRITEC = [&](int q) {
#pragma unroll
    for (int h = 0; h < 4; ++h)
      *(bf16x8*)&sB[q][64 * h + arow][achk] = rb[h];
  };
  LOADC(0);
  WRITEC(0);
  __syncthreads();
  cur = 0;
  for (int ks = 0; ks < 8; ++ks) {
    if (ks < 7) LOADC(32 * (ks + 1));
    const bf16x8 af = *(const bf16x8*)&sK[16 * rg + lr][32 * ks + fcol];
#pragma unroll
    for (int fc = 0; fc < 8; ++fc) {
      const bf16x8 bv = *(const bf16x8*)&sB[cur][128 * cg + 16 * fc + lr][fcol];
      acc2[fc] = __builtin_amdgcn_mfma_f32_16x16x32_bf16(af, bv, acc2[fc], 0, 0, 0);
    }
    if (ks < 7) WRITEC(cur ^ 1);
    __syncthreads();
    cur ^= 1;
  }

  // epilogue: M' = (acc2 + u r^T + w1 vs^T)/N + w1 r^T + I  (bf16)
  bf16_t* Mp = (bf16_t*)(ws + OFF_MP) + (size_t)b * 65536;
#pragma unroll
  for (int fc = 0; fc < 8; ++fc) {
    const int j = 128 * cg + 16 * fc + lr;
    const float rj = sR[j], vsj = sVS[j];
#pragma unroll
    for (int reg = 0; reg < 4; ++reg) {
      const int il = 16 * rg + 4 * hi + reg;
      const float ui = sU[il], w1i = sW1[i0 + il];
      float m = (acc2[fc][reg] + ui * rj + w1i * vsj) * INVN + w1i * rj;
      if (i0 + il == j) m += 1.0f;
      Mp[(size_t)(i0 + il) * CCH + j] = (bf16_t)m;
    }
  }
}

// ---------- Z^T 64-n tiles via MFMA, dbuf. APPLY=0: BN partials; 1: write out ----------
template <int APPLY>
__global__ __launch_bounds__(256) void k_zmm(float* __restrict__ ws, float* __restrict__ out) {
  const int b = blockIdx.y, nblk = blockIdx.x;      // 64 nblks of 64
  const int n0 = nblk * 64;
  const int t = threadIdx.x;
  const int w = t >> 6, lane = t & 63;
  const int rg = w >> 1, cg = w & 1;
  __shared__ __align__(16) bf16_t sA[2][64][40];
  __shared__ __align__(16) bf16_t sB[2][256][40];
  __shared__ float sC1[256], sC2[256];
  __shared__ float redS[4][128], redQ[4][128];
  {
    const float e = ws[OFF_E + b * CCH + t];
    if (APPLY) {
      const float sc = ws[OFF_SCALE + t];
      sC1[t] = sc;
      sC2[t] = e * sc + ws[OFF_SHIFT + t];
    } else {
      sC1[t] = e;
    }
  }
  const bf16_t* Xit = (const bf16_t*)(ws + OFF_XIT) + (size_t)b * NPIX * CCH;
  const bf16_t* Mp = (const bf16_t*)(ws + OFF_MP) + (size_t)b * 65536;
  const f32x4 z4 = {0.f, 0.f, 0.f, 0.f};
  f32x4 acc[2][8];
#pragma unroll
  for (int fr = 0; fr < 2; ++fr)
#pragma unroll
    for (int fc = 0; fc < 8; ++fc) acc[fr][fc] = z4;
  const int arow = t >> 2, achk = (t & 3) * 8;
  bf16x8 ra, rb0, rb1, rb2, rb3;
  ra  = *(const bf16x8*)(Xit + (size_t)(n0 + arow) * CCH + achk);
  rb0 = *(const bf16x8*)(Mp + (size_t)(arow)       * CCH + achk);
  rb1 = *(const bf16x8*)(Mp + (size_t)(64 + arow)  * CCH + achk);
  rb2 = *(const bf16x8*)(Mp + (size_t)(128 + arow) * CCH + achk);
  rb3 = *(const bf16x8*)(Mp + (size_t)(192 + arow) * CCH + achk);
  *(bf16x8*)&sA[0][arow][achk] = ra;
  *(bf16x8*)&sB[0][arow][achk] = rb0;
  *(bf16x8*)&sB[0][64 + arow][achk] = rb1;
  *(bf16x8*)&sB[0][128 + arow][achk] = rb2;
  *(bf16x8*)&sB[0][192 + arow][achk] = rb3;
  __syncthreads();
  int cur = 0;
  for (int ks = 0; ks < 8; ++ks) {
    const int nk = 32 * (ks + 1);
    if (ks < 7) {
      ra  = *(const bf16x8*)(Xit + (size_t)(n0 + arow) * CCH + nk + achk);
      rb0 = *(const bf16x8*)(Mp + (size_t)(arow)       * CCH + nk + achk);
      rb1 = *(const bf16x8*)(Mp + (size_t)(64 + arow)  * CCH + nk + achk);
      rb2 = *(const bf16x8*)(Mp + (size_t)(128 + arow) * CCH + nk + achk);
      rb3 = *(const bf16x8*)(Mp + (size_t)(192 + arow) * CCH + nk + achk);
    }
    const int fcol = 8 * (lane >> 4);
    const int lr = lane & 15;
    const bf16x8 af0 = *(const bf16x8*)&sA[cur][32 * rg + lr][fcol];
    const bf16x8 af1 = *(const bf16x8*)&sA[cur][32 * rg + 16 + lr][fcol];
#pragma unroll
    for (int fc = 0; fc < 8; ++fc) {
      const bf16x8 bv = *(const bf16x8*)&sB[cur][128 * cg + 16 * fc + lr][fcol];
      acc[0][fc] = __builtin_amdgcn_mfma_f32_16x16x32_bf16(af0, bv, acc[0][fc], 0, 0, 0);
      acc[1][fc] = __builtin_amdgcn_mfma_f32_16x16x32_bf16(af1, bv, acc[1][fc], 0, 0, 0);
    }
    if (ks < 7) {
      *(bf16x8*)&sA[cur ^ 1][arow][achk] = ra;
      *(bf16x8*)&sB[cur ^ 1][arow][achk] = rb0;
      *(bf16x8*)&sB[cur ^ 1][64 + arow][achk] = rb1;
      *(bf16x8*)&sB[cur ^ 1][128 + arow][achk] = rb2;
      *(bf16x8*)&sB[cur ^ 1][192 + arow][achk] = rb3;
    }
    __syncthreads();
    cur ^= 1;
  }
  if (APPLY) {
#pragma unroll
    for (int fc = 0; fc < 8; ++fc) {
      const int c = 128 * cg + 16 * fc + (lane & 15);
      const float sc = sC1[c], b2 = sC2[c];
      float* op = out + ((size_t)b * CCH + c) * NPIX + n0 + 32 * rg + ((lane >> 4) << 2);
#pragma unroll
      for (int fr = 0; fr < 2; ++fr) {
        float4 v;
        v.x = acc[fr][fc][0] * sc + b2;
        v.y = acc[fr][fc][1] * sc + b2;
        v.z = acc[fr][fc][2] * sc + b2;
        v.w = acc[fr][fc][3] * sc + b2;
        *(float4*)(op + 16 * fr) = v;
      }
    }
  } else {
    float ps[8], pq[8];
#pragma unroll
    for (int fc = 0; fc < 8; ++fc) {
      const int c = 128 * cg + 16 * fc + (lane & 15);
      const float e = sC1[c];
      float s = 0.f, q = 0.f;
#pragma unroll
      for (int fr = 0; fr < 2; ++fr)
#pragma unroll
        for (int reg = 0; reg < 4; ++reg) {
          const float z = acc[fr][fc][reg] + e;
          s += z; q += z * z;
        }
      s += __shfl_xor(s, 16); s += __shfl_xor(s, 32);
      q += __shfl_xor(q, 16); q += __shfl_xor(q, 32);
      ps[fc] = s; pq[fc] = q;
    }
    if (lane < 16) {
#pragma unroll
      for (int fc = 0; fc < 8; ++fc) {
        redS[w][16 * fc + lane] = ps[fc];
        redQ[w][16 * fc + lane] = pq[fc];
      }
    }
    __syncthreads();
    if (t < 256) {
      const int cg2 = t >> 7, c = t & 127;
      float s = 0.f, q = 0.f;
#pragma unroll
      for (int rg2 = 0; rg2 < 2; ++rg2) {
        s += redS[rg2 * 2 + cg2][c];
        q += redQ[rg2 * 2 + cg2][c];
      }
      ws[OFF_ZPS + (size_t)t * 512 + b * 64 + nblk] = s;
      ws[OFF_ZPQ + (size_t)t * 512 + b * 64 + nblk] = q;
    }
  }
}

// ---------- BN stats -> scale/shift ----------
__global__ __launch_bounds__(64) void k_bnstats(const float* __restrict__ gamma,
                                                const float* __restrict__ beta,
                                                float* __restrict__ ws) {
  const int c = blockIdx.x, t = threadIdx.x;
  const float* PS = ws + OFF_ZPS + (size_t)c * 512;
  const float* PQ = ws + OFF_ZPQ + (size_t)c * 512;
  float s = 0.f, q = 0.f;
#pragma unroll
  for (int e = 0; e < 8; ++e) { s += PS[t + 64 * e]; q += PQ[t + 64 * e]; }
#pragma unroll
  for (int off = 32; off; off >>= 1) { s += __shfl_down(s, off); q += __shfl_down(q, off); }
  if (t == 0) {
    const float mean = s * INVCNT;
    const float var = q * INVCNT - mean * mean;
    const float sc = gamma[c] * rsqrtf(var + 1e-5f);
    ws[OFF_SCALE + c] = sc;
    ws[OFF_SHIFT + c] = beta[c] - mean * sc;
  }
}

extern "C" void kernel_launch(void* const* d_in, const int* in_sizes, int n_in,
                              void* d_out, int out_size, void* d_ws, size_t ws_size,
                              hipStream_t stream) {
  const float* xi  = (const float*)d_in[0];
  const float* xj  = (const float*)d_in[1];
  const float* gw  = (const float*)d_in[2];
  const float* gb  = (const float*)d_in[3];
  const float* thw = (const float*)d_in[4];
  const float* thb = (const float*)d_in[5];
  const float* phw = (const float*)d_in[6];
  const float* phb = (const float*)d_in[7];
  const float* Ww  = (const float*)d_in[8];
  const float* Wb  = (const float*)d_in[9];
  const float* gamma = (const float*)d_in[10];
  const float* beta  = (const float*)d_in[11];
  float* ws = (float*)d_ws;
  float* out = (float*)d_out;

  k_mega<<<dim3(177, 8), 512, 0, stream>>>(xi, xj, Ww, gw, phw, thw, gb, phb, thb, ws);
  k_greduce<<<dim3(32, 8), 256, 0, stream>>>(ws);
  k_kmmat<<<dim3(8, 8), 256, 0, stream>>>(Wb, ws);
  k_zmm<0><<<dim3(64, 8), 256, 0, stream>>>(ws, out);
  k_bnstats<<<256, 64, 0, stream>>>(gamma, beta, ws);
  k_zmm<1><<<dim3(64, 8), 256, 0, stream>>>(ws, out);
}